// Round 1
// baseline (118.163 us; speedup 1.0000x reference)
//
#include <hip/hip_runtime.h>
#include <hip/hip_bf16.h>

#define NN 8192
#define CC 256
// exp(x/0.01) = exp2(x * 100 * log2(e))
#define ESCALE 144.26950408889634f

typedef __attribute__((ext_vector_type(8))) short short8;
typedef __attribute__((ext_vector_type(4))) float f32x4;

// ---------------- per-channel sum of squares (partials) ----------------
// grid 512: blocks 0..255 -> x rows [b*32, b*32+32); blocks 256..511 -> y
__global__ void colsumsq_kernel(const float* __restrict__ x, const float* __restrict__ y,
                                float* __restrict__ part) {
  const int b = blockIdx.x, t = threadIdx.x;
  const float* src = (b < 256) ? x : y;
  const int bb = b & 255;
  float s = 0.f;
#pragma unroll 4
  for (int r = 0; r < 32; ++r) {
    float v = src[(size_t)(bb * 32 + r) * CC + t];
    s = fmaf(v, v, s);
  }
  part[b * CC + t] = s;
}

// 1 block, 512 threads: t<256 -> inv_norm_x[c], t>=256 -> inv_norm_y[c]
__global__ void finnorm_kernel(const float* __restrict__ part, float* __restrict__ inv_n) {
  const int t = threadIdx.x;
  const int base = (t < 256) ? 0 : 256;
  const int c = t & 255;
  float s = 0.f;
  for (int b = 0; b < 256; ++b) s += part[(base + b) * CC + c];
  inv_n[t] = 1.0f / sqrtf(s);
}

// ---------------- normalize + convert to bf16 ----------------
__global__ void normconv_kernel(const float* __restrict__ src, const float* __restrict__ inv_n,
                                ushort* __restrict__ dst) {
  const int idx = (blockIdx.x * 256 + threadIdx.x) * 4;
  const float4 v = *(const float4*)(src + idx);
  const int c = idx & (CC - 1);
  float a0 = v.x * inv_n[c + 0];
  float a1 = v.y * inv_n[c + 1];
  float a2 = v.z * inv_n[c + 2];
  float a3 = v.w * inv_n[c + 3];
  __hip_bfloat16 h0 = __float2bfloat16(a0);
  __hip_bfloat16 h1 = __float2bfloat16(a1);
  __hip_bfloat16 h2 = __float2bfloat16(a2);
  __hip_bfloat16 h3 = __float2bfloat16(a3);
  ushort4 o;
  o.x = *(ushort*)&h0; o.y = *(ushort*)&h1; o.z = *(ushort*)&h2; o.w = *(ushort*)&h3;
  *(ushort4*)(dst + idx) = o;
}

// ---------------- main GEMM + fused epilogue ----------------
// 128x128 tile, 4 waves (2x2), BK=32, mfma_f32_16x16x32_bf16.
// Emits: per-block row-max partials, per-block col-sum(exp) partials,
// and stores corr rows 0..255 (blocks with rb<2) for the warped pass.
__global__ __launch_bounds__(256, 2)
void gemm_corr_kernel(const ushort* __restrict__ Xn, const ushort* __restrict__ Yn,
                      float* __restrict__ corr_top,     // [256][NN]
                      float* __restrict__ rowmax_part,  // [64][NN]  idx cb*NN + i
                      float* __restrict__ colsum_part)  // [64][NN]  idx rb*NN + j
{
  const int cb = blockIdx.x, rb = blockIdx.y;
  const int tid = threadIdx.x;
  const int lane = tid & 63, wid = tid >> 6;
  const int wr = wid >> 1, wc = wid & 1;
  const int q = lane >> 4;    // k-group / row-group selector
  const int lr = lane & 15;

  __shared__ __align__(16) ushort As[128 * 32];
  __shared__ __align__(16) ushort Bs[128 * 32];
  __shared__ float redbuf[2][128];

  f32x4 acc[4][4];
#pragma unroll
  for (int m = 0; m < 4; ++m)
#pragma unroll
    for (int n = 0; n < 4; ++n) acc[m][n] = (f32x4){0.f, 0.f, 0.f, 0.f};

  const int srow = tid >> 1;         // 0..127
  const int skc  = (tid & 1) * 16;   // 0 / 16
  const size_t gA = (size_t)(rb * 128 + srow) * CC + skc;
  const size_t gB = (size_t)(cb * 128 + srow) * CC + skc;

  for (int kk = 0; kk < CC; kk += 32) {
    const short8 va0 = *(const short8*)(Xn + gA + kk);
    const short8 va1 = *(const short8*)(Xn + gA + kk + 8);
    const short8 vb0 = *(const short8*)(Yn + gB + kk);
    const short8 vb1 = *(const short8*)(Yn + gB + kk + 8);
    *(short8*)(&As[srow * 32 + skc])     = va0;
    *(short8*)(&As[srow * 32 + skc + 8]) = va1;
    *(short8*)(&Bs[srow * 32 + skc])     = vb0;
    *(short8*)(&Bs[srow * 32 + skc + 8]) = vb1;
    __syncthreads();

    short8 af[4], bf[4];
#pragma unroll
    for (int m = 0; m < 4; ++m)
      af[m] = *(const short8*)(&As[(wr * 64 + m * 16 + lr) * 32 + q * 8]);
#pragma unroll
    for (int n = 0; n < 4; ++n)
      bf[n] = *(const short8*)(&Bs[(wc * 64 + n * 16 + lr) * 32 + q * 8]);

#pragma unroll
    for (int m = 0; m < 4; ++m)
#pragma unroll
      for (int n = 0; n < 4; ++n)
        acc[m][n] = __builtin_amdgcn_mfma_f32_16x16x32_bf16(af[m], bf[n], acc[m][n], 0, 0, 0);
    __syncthreads();
  }

  // ---- store top-256 corr rows for the warped pass ----
  if (rb < 2) {
    const int colg = cb * 128 + wc * 64 + lr;
#pragma unroll
    for (int m = 0; m < 4; ++m) {
      const int rowg = rb * 128 + wr * 64 + m * 16 + q * 4;
#pragma unroll
      for (int n = 0; n < 4; ++n)
#pragma unroll
        for (int r = 0; r < 4; ++r)
          corr_top[(size_t)(rowg + r) * NN + colg + n * 16] = acc[m][n][r];
    }
  }

  // ---- row max over this block's 128 columns ----
  // C/D layout: col = n*16 + (lane&15); row = m*16 + (lane>>4)*4 + r
#pragma unroll
  for (int m = 0; m < 4; ++m)
#pragma unroll
    for (int r = 0; r < 4; ++r) {
      float t = fmaxf(fmaxf(acc[m][0][r], acc[m][1][r]), fmaxf(acc[m][2][r], acc[m][3][r]));
      t = fmaxf(t, __shfl_xor(t, 1));
      t = fmaxf(t, __shfl_xor(t, 2));
      t = fmaxf(t, __shfl_xor(t, 4));
      t = fmaxf(t, __shfl_xor(t, 8));
      if (lr == 0) redbuf[wc][wr * 64 + m * 16 + q * 4 + r] = t;
    }
  __syncthreads();
  if (tid < 128)
    rowmax_part[(size_t)cb * NN + rb * 128 + tid] = fmaxf(redbuf[0][tid], redbuf[1][tid]);
  __syncthreads();

  // ---- column sum of exp(corr/tau) over this block's 128 rows ----
#pragma unroll
  for (int n = 0; n < 4; ++n) {
    float s = 0.f;
#pragma unroll
    for (int m = 0; m < 4; ++m)
#pragma unroll
      for (int r = 0; r < 4; ++r)
        s += exp2f(acc[m][n][r] * ESCALE);
    s += __shfl_xor(s, 16);
    s += __shfl_xor(s, 32);
    if (lane < 16) redbuf[wr][wc * 64 + n * 16 + lr] = s;
  }
  __syncthreads();
  if (tid < 128)
    colsum_part[(size_t)rb * NN + cb * 128 + tid] = redbuf[0][tid] + redbuf[1][tid];
}

// ---------------- reductions ----------------
__global__ void reduce_conf_kernel(const float* __restrict__ rowmax_part, float* __restrict__ out) {
  const int i = blockIdx.x * 256 + threadIdx.x;
  float m = -3.4e38f;
  for (int cb = 0; cb < 64; ++cb) m = fmaxf(m, rowmax_part[(size_t)cb * NN + i]);
  out[256 + i] = m;   // confidence_map after warped_color[256]
}

__global__ void reduce_s_kernel(const float* __restrict__ colsum_part, float* __restrict__ inv_s) {
  const int j = blockIdx.x * 256 + threadIdx.x;
  float s = 0.f;
  for (int rb = 0; rb < 64; ++rb) s += colsum_part[(size_t)rb * NN + j];
  inv_s[j] = 1.0f / s;
}

// ---------------- warped color: one block per k<256 ----------------
__global__ void warped_kernel(const float* __restrict__ corr_top, const float* __restrict__ inv_s,
                              const float* __restrict__ y, const float* __restrict__ inv_ny,
                              float* __restrict__ out) {
  const int k = blockIdx.x;
  const int tid = threadIdx.x;
  float p = 0.f;
  for (int j = tid; j < NN; j += 256) {
    float e = exp2f(corr_top[(size_t)k * NN + j] * ESCALE);
    p += e * inv_s[j] * y[(size_t)j * CC + k];
  }
#pragma unroll
  for (int d = 1; d < 64; d <<= 1) p += __shfl_xor(p, d);
  __shared__ float wsum[4];
  if ((tid & 63) == 0) wsum[tid >> 6] = p;
  __syncthreads();
  if (tid == 0) out[k] = (wsum[0] + wsum[1] + wsum[2] + wsum[3]) * inv_ny[k];
}

extern "C" void kernel_launch(void* const* d_in, const int* in_sizes, int n_in,
                              void* d_out, int out_size, void* d_ws, size_t ws_size,
                              hipStream_t stream) {
  const float* x = (const float*)d_in[0];
  const float* y = (const float*)d_in[1];
  float* out = (float*)d_out;
  char* ws = (char*)d_ws;

  ushort* xnb        = (ushort*)(ws);                       // 4 MB
  ushort* ynb        = (ushort*)(ws + (4u << 20));          // 4 MB
  float*  corr_top   = (float*)(ws + (8u << 20));           // 8 MB
  float*  rowmax_prt = (float*)(ws + (16u << 20));          // 2 MB
  float*  colsum_prt = (float*)(ws + (18u << 20));          // 2 MB
  float*  part       = (float*)(ws + (20u << 20));          // 512 KB
  float*  inv_n      = (float*)(ws + (20u << 20) + 524288); // 2 KB
  float*  inv_s      = (float*)(ws + (20u << 20) + 524288 + 4096); // 32 KB

  colsumsq_kernel<<<512, 256, 0, stream>>>(x, y, part);
  finnorm_kernel<<<1, 512, 0, stream>>>(part, inv_n);
  normconv_kernel<<<2048, 256, 0, stream>>>(x, inv_n, xnb);
  normconv_kernel<<<2048, 256, 0, stream>>>(y, inv_n + 256, ynb);
  gemm_corr_kernel<<<dim3(64, 64), 256, 0, stream>>>(xnb, ynb, corr_top, rowmax_prt, colsum_prt);
  reduce_conf_kernel<<<32, 256, 0, stream>>>(rowmax_prt, out);
  reduce_s_kernel<<<32, 256, 0, stream>>>(colsum_prt, inv_s);
  warped_kernel<<<256, 256, 0, stream>>>(corr_top, inv_s, y, inv_n + 256, out);
}

// Round 2
// 100.132 us; speedup vs baseline: 1.1801x; 1.1801x over previous
//
#include <hip/hip_runtime.h>
#include <hip/hip_bf16.h>

#define NN 8192
#define CC 256
// exp(x/0.01) = exp2(x * 100 * log2(e))
#define ESCALE 144.26950408889634f

typedef __attribute__((ext_vector_type(8))) short short8;
typedef __attribute__((ext_vector_type(4))) float f32x4;

typedef __attribute__((address_space(3))) unsigned int lds_u32;
typedef __attribute__((address_space(1))) const unsigned int glb_u32;

__device__ __forceinline__ void gload16(const ushort* g, ushort* l) {
  __builtin_amdgcn_global_load_lds((glb_u32*)(const void*)g, (lds_u32*)(void*)l, 16, 0, 0);
}

// ---------------- per-channel sum of squares (partials) ----------------
// grid 512: blocks 0..255 -> x rows [b*32, b*32+32); blocks 256..511 -> y
__global__ void colsumsq_kernel(const float* __restrict__ x, const float* __restrict__ y,
                                float* __restrict__ part) {
  const int b = blockIdx.x, t = threadIdx.x;
  const float* src = (b < 256) ? x : y;
  const int bb = b & 255;
  float s = 0.f;
#pragma unroll 4
  for (int r = 0; r < 32; ++r) {
    float v = src[(size_t)(bb * 32 + r) * CC + t];
    s = fmaf(v, v, s);
  }
  part[b * CC + t] = s;
}

// one wave per output norm: 512 outputs = 128 blocks x 4 waves
__global__ void finnorm_kernel(const float* __restrict__ part, float* __restrict__ inv_n) {
  const int g = blockIdx.x * 4 + (threadIdx.x >> 6);  // 0..511
  const int lane = threadIdx.x & 63;
  const int c = g & 255, T = g >> 8;
  float s = 0.f;
#pragma unroll
  for (int r = 0; r < 4; ++r)
    s += part[(size_t)((T << 8) + lane * 4 + r) * CC + c];
#pragma unroll
  for (int d = 1; d < 64; d <<= 1) s += __shfl_xor(s, d);
  if (lane == 0) inv_n[g] = 1.0f / sqrtf(s);
}

// ---------------- normalize + convert to bf16 (x and y fused) ----------------
__global__ void normconv_kernel(const float* __restrict__ x, const float* __restrict__ y,
                                const float* __restrict__ inv_n,
                                ushort* __restrict__ xnb, ushort* __restrict__ ynb) {
  int b = blockIdx.x;
  const float* src; ushort* dst; const float* inv;
  if (b < 2048) { src = x; dst = xnb; inv = inv_n; }
  else          { src = y; dst = ynb; inv = inv_n + 256; b -= 2048; }
  const int idx = (b * 256 + threadIdx.x) * 4;
  const float4 v = *(const float4*)(src + idx);
  const int c = idx & (CC - 1);
  __hip_bfloat16 h0 = __float2bfloat16(v.x * inv[c + 0]);
  __hip_bfloat16 h1 = __float2bfloat16(v.y * inv[c + 1]);
  __hip_bfloat16 h2 = __float2bfloat16(v.z * inv[c + 2]);
  __hip_bfloat16 h3 = __float2bfloat16(v.w * inv[c + 3]);
  ushort4 o;
  o.x = *(ushort*)&h0; o.y = *(ushort*)&h1; o.z = *(ushort*)&h2; o.w = *(ushort*)&h3;
  *(ushort4*)(dst + idx) = o;
}

// ---------------- main GEMM + fused epilogue ----------------
// 128x128 tile, 4 waves (2x2), BK=32, mfma_f32_16x16x32_bf16.
// Staging via global_load_lds width=16: LDS linear [128][32] ushort, chunk
// order == lane order (wave-uniform LDS base + per-lane global source).
__global__ __launch_bounds__(256, 2)
void gemm_corr_kernel(const ushort* __restrict__ Xn, const ushort* __restrict__ Yn,
                      float* __restrict__ corr_top,     // [256][NN]
                      float* __restrict__ rowmax_part,  // [64][NN]  idx cb*NN + i
                      float* __restrict__ colsum_part)  // [64][NN]  idx rb*NN + j
{
  const int cb = blockIdx.x, rb = blockIdx.y;
  const int tid = threadIdx.x;
  const int lane = tid & 63, wid = tid >> 6;
  const int wr = wid >> 1, wc = wid & 1;
  const int q = lane >> 4;    // k-group selector
  const int lr = lane & 15;

  __shared__ __align__(16) ushort As[128 * 32];
  __shared__ __align__(16) ushort Bs[128 * 32];
  __shared__ float redbuf[2][128];

  f32x4 acc[4][4];
#pragma unroll
  for (int m = 0; m < 4; ++m)
#pragma unroll
    for (int n = 0; n < 4; ++n) acc[m][n] = (f32x4){0.f, 0.f, 0.f, 0.f};

  // staging: chunk = r*256 + wid*64 + lane; row = chunk>>2; cq = chunk&3
  const int l2 = lane >> 2, cq = lane & 3;
  const size_t gA0 = (size_t)(rb * 128 +      wid * 16 + l2) * CC + cq * 8;
  const size_t gA1 = (size_t)(rb * 128 + 64 + wid * 16 + l2) * CC + cq * 8;
  const size_t gB0 = (size_t)(cb * 128 +      wid * 16 + l2) * CC + cq * 8;
  const size_t gB1 = (size_t)(cb * 128 + 64 + wid * 16 + l2) * CC + cq * 8;
  ushort* lA0 = As + wid * 512;
  ushort* lA1 = As + 2048 + wid * 512;
  ushort* lB0 = Bs + wid * 512;
  ushort* lB1 = Bs + 2048 + wid * 512;

  for (int kk = 0; kk < CC; kk += 32) {
    gload16(Xn + gA0 + kk, lA0);
    gload16(Xn + gA1 + kk, lA1);
    gload16(Yn + gB0 + kk, lB0);
    gload16(Yn + gB1 + kk, lB1);
    __syncthreads();   // drains vmcnt -> tiles resident

    short8 af[4], bf[4];
#pragma unroll
    for (int m = 0; m < 4; ++m)
      af[m] = *(const short8*)(&As[(wr * 64 + m * 16 + lr) * 32 + q * 8]);
#pragma unroll
    for (int n = 0; n < 4; ++n)
      bf[n] = *(const short8*)(&Bs[(wc * 64 + n * 16 + lr) * 32 + q * 8]);

#pragma unroll
    for (int m = 0; m < 4; ++m)
#pragma unroll
      for (int n = 0; n < 4; ++n)
        acc[m][n] = __builtin_amdgcn_mfma_f32_16x16x32_bf16(af[m], bf[n], acc[m][n], 0, 0, 0);
    __syncthreads();   // reads done before next overwrite
  }

  // ---- store top-256 corr rows for the warped pass ----
  if (rb < 2) {
    const int colg = cb * 128 + wc * 64 + lr;
#pragma unroll
    for (int m = 0; m < 4; ++m) {
      const int rowg = rb * 128 + wr * 64 + m * 16 + q * 4;
#pragma unroll
      for (int n = 0; n < 4; ++n)
#pragma unroll
        for (int r = 0; r < 4; ++r)
          corr_top[(size_t)(rowg + r) * NN + colg + n * 16] = acc[m][n][r];
    }
  }

  // ---- row max over this block's 128 columns ----
  // C/D layout: col = n*16 + (lane&15); row = m*16 + (lane>>4)*4 + r
#pragma unroll
  for (int m = 0; m < 4; ++m)
#pragma unroll
    for (int r = 0; r < 4; ++r) {
      float t = fmaxf(fmaxf(acc[m][0][r], acc[m][1][r]), fmaxf(acc[m][2][r], acc[m][3][r]));
      t = fmaxf(t, __shfl_xor(t, 1));
      t = fmaxf(t, __shfl_xor(t, 2));
      t = fmaxf(t, __shfl_xor(t, 4));
      t = fmaxf(t, __shfl_xor(t, 8));
      if (lr == 0) redbuf[wc][wr * 64 + m * 16 + q * 4 + r] = t;
    }
  __syncthreads();
  if (tid < 128)
    rowmax_part[(size_t)cb * NN + rb * 128 + tid] = fmaxf(redbuf[0][tid], redbuf[1][tid]);
  __syncthreads();

  // ---- column sum of exp(corr/tau) over this block's 128 rows ----
#pragma unroll
  for (int n = 0; n < 4; ++n) {
    float s = 0.f;
#pragma unroll
    for (int m = 0; m < 4; ++m)
#pragma unroll
      for (int r = 0; r < 4; ++r)
        s += exp2f(acc[m][n][r] * ESCALE);
    s += __shfl_xor(s, 16);
    s += __shfl_xor(s, 32);
    if (lane < 16) redbuf[wr][wc * 64 + n * 16 + lr] = s;
  }
  __syncthreads();
  if (tid < 128)
    colsum_part[(size_t)rb * NN + cb * 128 + tid] = redbuf[0][tid] + redbuf[1][tid];
}

// ---------------- fused reductions: one wave per output ----------------
// g in [0,8192): confidence row-max ; g in [8192,16384): column softmax denom
__global__ void reduce_both_kernel(const float* __restrict__ rowmax_part,
                                   const float* __restrict__ colsum_part,
                                   float* __restrict__ out, float* __restrict__ inv_s) {
  const int g = blockIdx.x * 4 + (threadIdx.x >> 6);
  const int lane = threadIdx.x & 63;
  if (g < 8192) {
    float v = rowmax_part[(size_t)lane * NN + g];
#pragma unroll
    for (int d = 1; d < 64; d <<= 1) v = fmaxf(v, __shfl_xor(v, d));
    if (lane == 0) out[256 + g] = v;
  } else {
    const int j = g - 8192;
    float v = colsum_part[(size_t)lane * NN + j];
#pragma unroll
    for (int d = 1; d < 64; d <<= 1) v += __shfl_xor(v, d);
    if (lane == 0) inv_s[j] = 1.0f / v;
  }
}

// ---------------- warped color: one block per k<256 ----------------
__global__ void warped_kernel(const float* __restrict__ corr_top, const float* __restrict__ inv_s,
                              const float* __restrict__ y, const float* __restrict__ inv_ny,
                              float* __restrict__ out) {
  const int k = blockIdx.x;
  const int tid = threadIdx.x;
  float p = 0.f;
  for (int j = tid; j < NN; j += 256) {
    float e = exp2f(corr_top[(size_t)k * NN + j] * ESCALE);
    p += e * inv_s[j] * y[(size_t)j * CC + k];
  }
#pragma unroll
  for (int d = 1; d < 64; d <<= 1) p += __shfl_xor(p, d);
  __shared__ float wsum[4];
  if ((tid & 63) == 0) wsum[tid >> 6] = p;
  __syncthreads();
  if (tid == 0) out[k] = (wsum[0] + wsum[1] + wsum[2] + wsum[3]) * inv_ny[k];
}

extern "C" void kernel_launch(void* const* d_in, const int* in_sizes, int n_in,
                              void* d_out, int out_size, void* d_ws, size_t ws_size,
                              hipStream_t stream) {
  const float* x = (const float*)d_in[0];
  const float* y = (const float*)d_in[1];
  float* out = (float*)d_out;
  char* ws = (char*)d_ws;

  ushort* xnb        = (ushort*)(ws);                       // 4 MB
  ushort* ynb        = (ushort*)(ws + (4u << 20));          // 4 MB
  float*  corr_top   = (float*)(ws + (8u << 20));           // 8 MB
  float*  rowmax_prt = (float*)(ws + (16u << 20));          // 2 MB
  float*  colsum_prt = (float*)(ws + (18u << 20));          // 2 MB
  float*  part       = (float*)(ws + (20u << 20));          // 512 KB
  float*  inv_n      = (float*)(ws + (20u << 20) + 524288); // 2 KB
  float*  inv_s      = (float*)(ws + (20u << 20) + 524288 + 4096); // 32 KB

  colsumsq_kernel<<<512, 256, 0, stream>>>(x, y, part);
  finnorm_kernel<<<128, 256, 0, stream>>>(part, inv_n);
  normconv_kernel<<<4096, 256, 0, stream>>>(x, y, inv_n, xnb, ynb);
  gemm_corr_kernel<<<dim3(64, 64), 256, 0, stream>>>(xnb, ynb, corr_top, rowmax_prt, colsum_prt);
  reduce_both_kernel<<<4096, 256, 0, stream>>>(rowmax_prt, colsum_prt, out, inv_s);
  warped_kernel<<<256, 256, 0, stream>>>(corr_top, inv_s, y, inv_n + 256, out);
}